// Round 1
// baseline (109.275 us; speedup 1.0000x reference)
//
#include <hip/hip_runtime.h>
#include <hip/hip_bf16.h>

// Problem constants (fixed-shape problem)
#define DD    64            // H == W == 64
#define PP    4096          // pixels per image
#define NPTS  4096          // points per image
#define NB    8             // batch
#define CCH   64            // image channels
#define FXF   32            // extra features
#define KIN   96            // CCH + FXF
#define DOUT  256
#define NTOT  (NB*NPTS)     // 32768 points

#define MTILE  64           // points per block (fused kernel)
#define HSTR   100          // padded LDS stride for h (keeps 16B align: 400B rows)
#define WCHUNK 16           // W rows staged per LDS chunk

// ---------------------------------------------------------------------------
// K0: transpose images [B][C][P] -> pix [B][P][C]  (makes per-pixel gathers
// contiguous 256B rows)
// ---------------------------------------------------------------------------
__global__ __launch_bounds__(256) void k_transpose(const float* __restrict__ img,
                                                   float* __restrict__ pix)
{
    __shared__ float tile[32][33];
    const int b  = blockIdx.z;
    const int p0 = blockIdx.x * 32;   // pixel tile
    const int c0 = blockIdx.y * 32;   // channel tile
    const int tx = threadIdx.x, ty = threadIdx.y;

    const float* src = img + (size_t)b * CCH * PP;
    float*       dst = pix + (size_t)b * PP * CCH;

#pragma unroll
    for (int i = 0; i < 32; i += 8)
        tile[ty + i][tx] = src[(size_t)(c0 + ty + i) * PP + (p0 + tx)];
    __syncthreads();
#pragma unroll
    for (int i = 0; i < 32; i += 8)
        dst[(size_t)(p0 + ty + i) * CCH + (c0 + tx)] = tile[tx][ty + i];
}

// ---------------------------------------------------------------------------
// K1: fused  (3-NN interp on regular grid -> h in LDS -> f32 GEMM -> out)
//   block: 256 threads, MTILE=64 points.  Phase A: 4 threads/point.
//   Phase B: thread (ty=t>>6, tx=t&63) computes 16 points x 4 douts.
// ---------------------------------------------------------------------------
__global__ __launch_bounds__(256) void k_fused(const float* __restrict__ pix,
                                               const float* __restrict__ x,
                                               const float* __restrict__ pos,
                                               const float* __restrict__ Wn,
                                               const float* __restrict__ bn,
                                               float* __restrict__ out)
{
    __shared__ float h_lds[MTILE][HSTR];          // 25.6 KB
    __shared__ float w_lds[WCHUNK][DOUT];         // 16 KB

    const int t   = threadIdx.x;
    const int pt0 = blockIdx.x * MTILE;

    // ---------------- Phase A: interpolation + concat into LDS -------------
    {
        const int lp  = t >> 2;                   // local point 0..63
        const int q   = t & 3;                    // quarter (16 channels each)
        const int gpt = pt0 + lp;
        const float px = pos[2 * gpt + 0];
        const float py = pos[2 * gpt + 1];
        const int   b  = gpt >> 12;               // NPTS = 4096 points/image

        // Replicate reference d2 rounding:  (|p|^2 + |c|^2) - 2*(p.c)
        const float spt = __fadd_rn(__fmul_rn(px, px), __fmul_rn(py, py));

        int cc = (int)floorf(px * 64.0f); cc = min(max(cc, 0), DD - 1);
        int rr = (int)floorf(py * 64.0f); rr = min(max(rr, 0), DD - 1);
        const int c0 = min(max(cc - 1, 0), DD - 3);
        const int r0 = min(max(rr - 1, 0), DD - 3);

        float bd0 = 1e30f, bd1 = 1e30f, bd2 = 1e30f;
        int   bp0 = 0,     bp1 = 0,     bp2 = 0;
#pragma unroll
        for (int dr = 0; dr < 3; ++dr) {
            const int   r  = r0 + dr;
            const float cy = ((float)r + 0.5f) * 0.015625f;   // exact
#pragma unroll
            for (int dc = 0; dc < 3; ++dc) {
                const int   c  = c0 + dc;
                const float cx = ((float)c + 0.5f) * 0.015625f;
                const float spp = __fadd_rn(__fmul_rn(cx, cx), __fmul_rn(cy, cy));
                const float dt  = __fmaf_rn(py, cy, __fmul_rn(px, cx));
                const float d2  = __fsub_rn(__fadd_rn(spt, spp), __fmul_rn(2.0f, dt));
                const int   p   = r * DD + c;
                // strict < keeps earlier (smaller p) on ties == top_k tie-break
                if (d2 < bd2) {
                    if (d2 < bd1) {
                        if (d2 < bd0) { bd2 = bd1; bp2 = bp1; bd1 = bd0; bp1 = bp0; bd0 = d2; bp0 = p; }
                        else          { bd2 = bd1; bp2 = bp1; bd1 = d2;  bp1 = p; }
                    } else            { bd2 = d2;  bp2 = p; }
                }
            }
        }

        const float w0 = 1.0f / fmaxf(bd0, 1e-16f);
        const float w1 = 1.0f / fmaxf(bd1, 1e-16f);
        const float w2 = 1.0f / fmaxf(bd2, 1e-16f);
        const float inv = 1.0f / (w0 + w1 + w2);

        const float* g0p = pix + ((size_t)(b * PP + bp0)) * CCH + q * 16;
        const float* g1p = pix + ((size_t)(b * PP + bp1)) * CCH + q * 16;
        const float* g2p = pix + ((size_t)(b * PP + bp2)) * CCH + q * 16;
#pragma unroll
        for (int m = 0; m < 4; ++m) {
            const float4 g0 = ((const float4*)g0p)[m];
            const float4 g1 = ((const float4*)g1p)[m];
            const float4 g2 = ((const float4*)g2p)[m];
            float4 s;
            s.x = (w0 * g0.x + w1 * g1.x + w2 * g2.x) * inv;
            s.y = (w0 * g0.y + w1 * g1.y + w2 * g2.y) * inv;
            s.z = (w0 * g0.z + w1 * g1.z + w2 * g2.z) * inv;
            s.w = (w0 * g0.w + w1 * g1.w + w2 * g2.w) * inv;
            *(float4*)&h_lds[lp][q * 16 + m * 4] = s;
        }
        // x part: 8 floats per thread
        const float* xr = x + (size_t)gpt * FXF + q * 8;
        const float4 xa = ((const float4*)xr)[0];
        const float4 xb = ((const float4*)xr)[1];
        *(float4*)&h_lds[lp][CCH + q * 8 + 0] = xa;
        *(float4*)&h_lds[lp][CCH + q * 8 + 4] = xb;
    }
    __syncthreads();

    // ---------------- Phase B: [64 x 96] @ [96 x 256] f32 GEMM -------------
    const int tx = t & 63;        // dout group: douts tx*4 .. tx*4+3
    const int ty = t >> 6;        // point group: points ty*16 .. ty*16+15

    float4 acc[16];
#pragma unroll
    for (int i = 0; i < 16; ++i) acc[i] = make_float4(0.f, 0.f, 0.f, 0.f);

    const float4 bias = *(const float4*)(bn + tx * 4);

    for (int k0 = 0; k0 < KIN; k0 += WCHUNK) {
        __syncthreads();  // protect w_lds reuse
        const float4* wsrc = (const float4*)(Wn + (size_t)k0 * DOUT);
#pragma unroll
        for (int j = 0; j < 4; ++j)
            ((float4*)&w_lds[0][0])[t + 256 * j] = wsrc[t + 256 * j];
        __syncthreads();

#pragma unroll
        for (int kk = 0; kk < WCHUNK; kk += 4) {
            const float4 wv0 = *(const float4*)&w_lds[kk + 0][tx * 4];
            const float4 wv1 = *(const float4*)&w_lds[kk + 1][tx * 4];
            const float4 wv2 = *(const float4*)&w_lds[kk + 2][tx * 4];
            const float4 wv3 = *(const float4*)&w_lds[kk + 3][tx * 4];
#pragma unroll
            for (int i = 0; i < 16; ++i) {
                const float4 hv = *(const float4*)&h_lds[ty * 16 + i][k0 + kk];
                acc[i].x = fmaf(hv.x, wv0.x, fmaf(hv.y, wv1.x, fmaf(hv.z, wv2.x, fmaf(hv.w, wv3.x, acc[i].x))));
                acc[i].y = fmaf(hv.x, wv0.y, fmaf(hv.y, wv1.y, fmaf(hv.z, wv2.y, fmaf(hv.w, wv3.y, acc[i].y))));
                acc[i].z = fmaf(hv.x, wv0.z, fmaf(hv.y, wv1.z, fmaf(hv.z, wv2.z, fmaf(hv.w, wv3.z, acc[i].z))));
                acc[i].w = fmaf(hv.x, wv0.w, fmaf(hv.y, wv1.w, fmaf(hv.z, wv2.w, fmaf(hv.w, wv3.w, acc[i].w))));
            }
        }
    }

#pragma unroll
    for (int i = 0; i < 16; ++i) {
        float4 o;
        o.x = acc[i].x + bias.x; o.y = acc[i].y + bias.y;
        o.z = acc[i].z + bias.z; o.w = acc[i].w + bias.w;
        *(float4*)(out + ((size_t)(pt0 + ty * 16 + i)) * DOUT + tx * 4) = o;
    }
}

// ---------------------------------------------------------------------------
extern "C" void kernel_launch(void* const* d_in, const int* in_sizes, int n_in,
                              void* d_out, int out_size, void* d_ws, size_t ws_size,
                              hipStream_t stream)
{
    const float* images = (const float*)d_in[0];  // [8,64,64,64]
    const float* x      = (const float*)d_in[1];  // [32768,32]
    const float* pos    = (const float*)d_in[2];  // [32768,2]
    // d_in[3] = batch (int64)  -- recomputed as gpt>>12
    const float* W_nn   = (const float*)d_in[4];  // [96,256]
    const float* b_nn   = (const float*)d_in[5];  // [256]
    // d_in[6] = k (==3)        -- hardcoded
    float* out = (float*)d_out;

    float* pix = (float*)d_ws;                    // [8,4096,64] = 8 MB

    k_transpose<<<dim3(PP / 32, CCH / 32, NB), dim3(32, 8), 0, stream>>>(images, pix);
    k_fused<<<NTOT / MTILE, 256, 0, stream>>>(pix, x, pos, W_nn, b_nn, out);
}

// Round 2
// 105.164 us; speedup vs baseline: 1.0391x; 1.0391x over previous
//
#include <hip/hip_runtime.h>
#include <hip/hip_bf16.h>

// Problem constants (fixed-shape problem)
#define DD    64            // H == W == 64
#define PP    4096          // pixels per image
#define NPTS  4096          // points per image
#define NB    8             // batch
#define CCH   64            // image channels
#define FXF   32            // extra features
#define KIN   96            // CCH + FXF
#define DOUT  256
#define NTOT  (NB*NPTS)     // 32768 points

#define MTILE  64           // points per block (fused kernel)
#define HSTR   100          // padded LDS stride for h (400B rows, 16B aligned)
#define WCHUNK 16           // W rows staged per LDS chunk
#define NCHUNK (KIN / WCHUNK)   // 6

// ---------------------------------------------------------------------------
// K0: transpose images [B][C][P] -> pix [B][P][C].
//   64ch x 64pix tile per block; loads 1KiB/wave-inst (float4), stores 256B
//   contiguous per wave-inst. LDS pad +1 float -> 2-way bank alias (free).
// ---------------------------------------------------------------------------
__global__ __launch_bounds__(256) void k_transpose(const float* __restrict__ img,
                                                   float* __restrict__ pix)
{
    __shared__ float tile[64][65];
    const int b  = blockIdx.z;
    const int p0 = blockIdx.x * 64;   // pixel tile base
    const int t  = threadIdx.x;

    const float* src = img + (size_t)b * CCH * PP;
    float*       dst = pix + (size_t)b * PP * CCH;

    // load: thread (p4 = t&15, ch = t>>4) reads float4 along pixels
    {
        const int p4 = t & 15;
        const int ch = t >> 4;        // 0..15
#pragma unroll
        for (int i = 0; i < 64; i += 16) {
            const float4 v = ((const float4*)(src + (size_t)(ch + i) * PP + p0))[p4];
            *(float4*)&tile[ch + i][p4 * 4] = v;
        }
    }
    __syncthreads();
    // store: thread (ch = t&63, py = t>>6) writes dst[pix][ch], 256B/wave
    {
        const int ch = t & 63;
        const int py = t >> 6;        // 0..3
#pragma unroll
        for (int i = 0; i < 64; i += 4)
            dst[(size_t)(p0 + py + i) * CCH + ch] = tile[ch][py + i];
    }
}

// ---------------------------------------------------------------------------
// K1: fused  (3-NN interp on regular grid -> h in LDS -> f32 GEMM -> out)
//   512 threads, MTILE=64 points.
//   Phase A: 8 threads/point (8 channels each).
//   Phase B: thread (ty=t>>6 in 0..7, tx=t&63) -> 8 points x 4 douts.
//   W-chunk register-prefetched across the barrier (issue-early/write-late).
// ---------------------------------------------------------------------------
__global__ __launch_bounds__(512, 4) void k_fused(const float* __restrict__ pix,
                                                  const float* __restrict__ x,
                                                  const float* __restrict__ pos,
                                                  const float* __restrict__ Wn,
                                                  const float* __restrict__ bn,
                                                  float* __restrict__ out)
{
    __shared__ float h_lds[MTILE][HSTR];          // 25.6 KB
    __shared__ float w_lds[WCHUNK * DOUT];        // 16 KB

    const int t   = threadIdx.x;
    const int pt0 = blockIdx.x * MTILE;

    // ---------------- Phase A: interpolation + concat into LDS -------------
    {
        const int lp  = t >> 3;                   // local point 0..63
        const int q   = t & 7;                    // 8-channel slice
        const int gpt = pt0 + lp;
        const float2 pp = ((const float2*)pos)[gpt];
        const float px = pp.x;
        const float py = pp.y;
        const int   b  = gpt >> 12;               // NPTS = 4096 points/image

        // Replicate reference d2 rounding:  (|p|^2 + |c|^2) - 2*(p.c)
        const float spt = __fadd_rn(__fmul_rn(px, px), __fmul_rn(py, py));

        int cc = (int)floorf(px * 64.0f); cc = min(max(cc, 0), DD - 1);
        int rr = (int)floorf(py * 64.0f); rr = min(max(rr, 0), DD - 1);
        const int c0 = min(max(cc - 1, 0), DD - 3);
        const int r0 = min(max(rr - 1, 0), DD - 3);

        float bd0 = 1e30f, bd1 = 1e30f, bd2 = 1e30f;
        int   bp0 = 0,     bp1 = 0,     bp2 = 0;
#pragma unroll
        for (int dr = 0; dr < 3; ++dr) {
            const int   r  = r0 + dr;
            const float cy = ((float)r + 0.5f) * 0.015625f;   // exact
#pragma unroll
            for (int dc = 0; dc < 3; ++dc) {
                const int   c  = c0 + dc;
                const float cx = ((float)c + 0.5f) * 0.015625f;
                const float spp = __fadd_rn(__fmul_rn(cx, cx), __fmul_rn(cy, cy));
                const float dt  = __fmaf_rn(py, cy, __fmul_rn(px, cx));
                const float d2  = __fsub_rn(__fadd_rn(spt, spp), __fmul_rn(2.0f, dt));
                const int   p   = r * DD + c;
                // strict < keeps earlier (smaller p) on ties == top_k tie-break
                if (d2 < bd2) {
                    if (d2 < bd1) {
                        if (d2 < bd0) { bd2 = bd1; bp2 = bp1; bd1 = bd0; bp1 = bp0; bd0 = d2; bp0 = p; }
                        else          { bd2 = bd1; bp2 = bp1; bd1 = d2;  bp1 = p; }
                    } else            { bd2 = d2;  bp2 = p; }
                }
            }
        }

        const float w0 = 1.0f / fmaxf(bd0, 1e-16f);
        const float w1 = 1.0f / fmaxf(bd1, 1e-16f);
        const float w2 = 1.0f / fmaxf(bd2, 1e-16f);
        const float inv = 1.0f / (w0 + w1 + w2);

        const float* g0p = pix + ((size_t)(b * PP + bp0)) * CCH + q * 8;
        const float* g1p = pix + ((size_t)(b * PP + bp1)) * CCH + q * 8;
        const float* g2p = pix + ((size_t)(b * PP + bp2)) * CCH + q * 8;
#pragma unroll
        for (int m = 0; m < 2; ++m) {
            const float4 g0 = ((const float4*)g0p)[m];
            const float4 g1 = ((const float4*)g1p)[m];
            const float4 g2 = ((const float4*)g2p)[m];
            float4 s;
            s.x = (w0 * g0.x + w1 * g1.x + w2 * g2.x) * inv;
            s.y = (w0 * g0.y + w1 * g1.y + w2 * g2.y) * inv;
            s.z = (w0 * g0.z + w1 * g1.z + w2 * g2.z) * inv;
            s.w = (w0 * g0.w + w1 * g1.w + w2 * g2.w) * inv;
            *(float4*)&h_lds[lp][q * 8 + m * 4] = s;
        }
        // x part: 4 floats per thread
        const float4 xv = *(const float4*)(x + (size_t)gpt * FXF + q * 4);
        *(float4*)&h_lds[lp][CCH + q * 4] = xv;
    }

    // ---------------- Phase B: [64 x 96] @ [96 x 256] f32 GEMM -------------
    const int tx = t & 63;        // dout group: douts tx*4 .. tx*4+3
    const int ty = t >> 6;        // point group: points ty*8 .. ty*8+7

    float4 acc[8];
#pragma unroll
    for (int i = 0; i < 8; ++i) acc[i] = make_float4(0.f, 0.f, 0.f, 0.f);

    const float4 bias = *(const float4*)(bn + tx * 4);

    // prefetch W chunk 0 into registers
    float4 wpre0 = ((const float4*)Wn)[t];
    float4 wpre1 = ((const float4*)Wn)[t + 512];

    for (int c = 0; c < NCHUNK; ++c) {
        __syncthreads();          // Phase-A h ready (c=0) / readers done (c>0)
        ((float4*)w_lds)[t]       = wpre0;
        ((float4*)w_lds)[t + 512] = wpre1;
        if (c + 1 < NCHUNK) {     // issue next chunk early; lands after barrier
            const float4* wsrc = (const float4*)(Wn + (size_t)(c + 1) * WCHUNK * DOUT);
            wpre0 = wsrc[t];
            wpre1 = wsrc[t + 512];
        }
        __syncthreads();

        const int k0 = c * WCHUNK;
#pragma unroll
        for (int kk = 0; kk < WCHUNK; kk += 4) {
            const float4 wv0 = *(const float4*)&w_lds[(kk + 0) * DOUT + tx * 4];
            const float4 wv1 = *(const float4*)&w_lds[(kk + 1) * DOUT + tx * 4];
            const float4 wv2 = *(const float4*)&w_lds[(kk + 2) * DOUT + tx * 4];
            const float4 wv3 = *(const float4*)&w_lds[(kk + 3) * DOUT + tx * 4];
#pragma unroll
            for (int i = 0; i < 8; ++i) {
                const float4 hv = *(const float4*)&h_lds[ty * 8 + i][k0 + kk];
                acc[i].x = fmaf(hv.x, wv0.x, fmaf(hv.y, wv1.x, fmaf(hv.z, wv2.x, fmaf(hv.w, wv3.x, acc[i].x))));
                acc[i].y = fmaf(hv.x, wv0.y, fmaf(hv.y, wv1.y, fmaf(hv.z, wv2.y, fmaf(hv.w, wv3.y, acc[i].y))));
                acc[i].z = fmaf(hv.x, wv0.z, fmaf(hv.y, wv1.z, fmaf(hv.z, wv2.z, fmaf(hv.w, wv3.z, acc[i].z))));
                acc[i].w = fmaf(hv.x, wv0.w, fmaf(hv.y, wv1.w, fmaf(hv.z, wv2.w, fmaf(hv.w, wv3.w, acc[i].w))));
            }
        }
    }

#pragma unroll
    for (int i = 0; i < 8; ++i) {
        float4 o;
        o.x = acc[i].x + bias.x; o.y = acc[i].y + bias.y;
        o.z = acc[i].z + bias.z; o.w = acc[i].w + bias.w;
        *(float4*)(out + ((size_t)(pt0 + ty * 8 + i)) * DOUT + tx * 4) = o;
    }
}

// ---------------------------------------------------------------------------
extern "C" void kernel_launch(void* const* d_in, const int* in_sizes, int n_in,
                              void* d_out, int out_size, void* d_ws, size_t ws_size,
                              hipStream_t stream)
{
    const float* images = (const float*)d_in[0];  // [8,64,64,64]
    const float* x      = (const float*)d_in[1];  // [32768,32]
    const float* pos    = (const float*)d_in[2];  // [32768,2]
    // d_in[3] = batch (int64)  -- recomputed as gpt>>12
    const float* W_nn   = (const float*)d_in[4];  // [96,256]
    const float* b_nn   = (const float*)d_in[5];  // [256]
    // d_in[6] = k (==3)        -- hardcoded
    float* out = (float*)d_out;

    float* pix = (float*)d_ws;                    // [8,4096,64] = 8 MB

    k_transpose<<<dim3(PP / 64, 1, NB), 256, 0, stream>>>(images, pix);
    k_fused<<<NTOT / MTILE, 512, 0, stream>>>(pix, x, pos, W_nn, b_nn, out);
}

// Round 3
// 96.054 us; speedup vs baseline: 1.1376x; 1.0948x over previous
//
#include <hip/hip_runtime.h>
#include <hip/hip_bf16.h>

// Problem constants (fixed-shape problem)
#define DD    64            // H == W == 64
#define PP    4096          // pixels per image
#define NPTS  4096          // points per image
#define NB    8             // batch
#define CCH   64            // image channels
#define FXF   32            // extra features
#define KIN   96            // CCH + FXF
#define DOUT  256
#define NTOT  (NB*NPTS)     // 32768 points

#define MTILE 64            // points per block (fused kernel)
#define KSTEPS 3            // 96 / 32
#define NWAVES 4            // waves per fused block; wave w owns douts [64w,64w+64)

typedef float  f32x4  __attribute__((ext_vector_type(4)));
typedef short  short8 __attribute__((ext_vector_type(8)));

// RNE f32 -> bf16 bits, and exact split v = hi + lo (each bf16).
__device__ __forceinline__ void split_bf16(float v, unsigned short& hi, unsigned short& lo)
{
    union { float f; unsigned u; } a;
    a.f = v;
    unsigned r = (a.u + 0x7FFFu + ((a.u >> 16) & 1u)) >> 16;   // RNE
    hi = (unsigned short)r;
    union { unsigned u; float f; } b;
    b.u = r << 16;
    float rem = v - b.f;                                        // exact (Sterbenz)
    a.f = rem;
    unsigned r2 = (a.u + 0x7FFFu + ((a.u >> 16) & 1u)) >> 16;
    lo = (unsigned short)r2;
}

// ---------------------------------------------------------------------------
// K0: transpose images [B][C][P] -> pix [B][P][C]
// ---------------------------------------------------------------------------
__global__ __launch_bounds__(256) void k_transpose(const float* __restrict__ img,
                                                   float* __restrict__ pix)
{
    __shared__ float tile[64][65];
    const int b  = blockIdx.z;
    const int p0 = blockIdx.x * 64;
    const int t  = threadIdx.x;

    const float* src = img + (size_t)b * CCH * PP;
    float*       dst = pix + (size_t)b * PP * CCH;

    {
        const int p4 = t & 15;
        const int ch = t >> 4;
#pragma unroll
        for (int i = 0; i < 64; i += 16) {
            const float4 v = ((const float4*)(src + (size_t)(ch + i) * PP + p0))[p4];
            *(float4*)&tile[ch + i][p4 * 4] = v;
        }
    }
    __syncthreads();
    {
        const int ch = t & 63;
        const int py = t >> 6;
#pragma unroll
        for (int i = 0; i < 64; i += 4)
            dst[(size_t)(p0 + py + i) * CCH + ch] = tile[ch][py + i];
    }
}

// ---------------------------------------------------------------------------
// K0b: split W (96x256 f32) into bf16 hi/lo MFMA B-fragments.
// Layout: [n 4][kstep 3][pass 2][n_rep 4][lane 64][b 8] ushort; per-lane 8
// contiguous ushorts = 16B so k_fused loads each fragment as one b128.
// Fragment semantics: lane l holds W[kstep*32 + 8*(l>>4) + b][n*64 + nr*16 + (l&15)].
// ---------------------------------------------------------------------------
__global__ __launch_bounds__(256) void k_wsplit(const float* __restrict__ Wn,
                                                unsigned short* __restrict__ wfrag)
{
    const int t = blockIdx.x * 256 + threadIdx.x;   // 0 .. 24575
    const int b  = t & 7;
    const int l  = (t >> 3) & 63;
    const int v  = t >> 9;          // [0,48) over [n][ks][nr]
    const int nr = v & 3;
    const int w  = v >> 2;          // [0,12)
    const int ks = w % 3;
    const int n  = w / 3;

    const int k = ks * 32 + 8 * (l >> 4) + b;
    const int d = n * 64 + nr * 16 + (l & 15);
    const float val = Wn[k * DOUT + d];

    unsigned short hi, lo;
    split_bf16(val, hi, lo);
    const int base = (((n * 3 + ks) * 2 + 0) * 4 + nr) * 512 + l * 8 + b;
    const int basl = (((n * 3 + ks) * 2 + 1) * 4 + nr) * 512 + l * 8 + b;
    wfrag[base] = hi;
    wfrag[basl] = lo;
}

// ---------------------------------------------------------------------------
// K1: fused  (3-NN interp -> split-bf16 h in LDS -> MFMA GEMM -> out)
//   256 threads = 4 waves; block tile 64 points x 256 douts.
//   Wave w: douts [64w, 64w+64) -> 4x4 fragments of 16x16, K=96 in 3 steps.
//   Split-bf16: acc += Ah*Wh + Al*Wh + Ah*Wl   (~2^-17 relative accuracy)
// ---------------------------------------------------------------------------
__global__ __launch_bounds__(256, 4) void k_fused(const float* __restrict__ pix,
                                                  const float* __restrict__ x,
                                                  const float* __restrict__ pos,
                                                  const unsigned short* __restrict__ wfrag,
                                                  const float* __restrict__ bn,
                                                  float* __restrict__ out)
{
    __shared__ __align__(16) unsigned short h_hi[MTILE][KIN];   // 12 KB
    __shared__ __align__(16) unsigned short h_lo[MTILE][KIN];   // 12 KB

    const int t    = threadIdx.x;
    const int lane = t & 63;
    const int wv   = t >> 6;
    const int pt0  = blockIdx.x * MTILE;

    // ---------------- Phase A: interpolation + concat (split-bf16) ---------
    {
        const int lp  = t >> 2;                   // local point 0..63
        const int q   = t & 3;                    // 16-channel slice
        const int gpt = pt0 + lp;
        const float2 pp = ((const float2*)pos)[gpt];
        const float px = pp.x;
        const float py = pp.y;
        const int   b  = gpt >> 12;               // NPTS = 4096 points/image

        // Replicate reference d2 rounding:  (|p|^2 + |c|^2) - 2*(p.c)
        const float spt = __fadd_rn(__fmul_rn(px, px), __fmul_rn(py, py));

        int cc = (int)floorf(px * 64.0f); cc = min(max(cc, 0), DD - 1);
        int rr = (int)floorf(py * 64.0f); rr = min(max(rr, 0), DD - 1);
        const int c0 = min(max(cc - 1, 0), DD - 3);
        const int r0 = min(max(rr - 1, 0), DD - 3);

        float bd0 = 1e30f, bd1 = 1e30f, bd2 = 1e30f;
        int   bp0 = 0,     bp1 = 0,     bp2 = 0;
#pragma unroll
        for (int dr = 0; dr < 3; ++dr) {
            const int   r  = r0 + dr;
            const float cy = ((float)r + 0.5f) * 0.015625f;
#pragma unroll
            for (int dc = 0; dc < 3; ++dc) {
                const int   c  = c0 + dc;
                const float cx = ((float)c + 0.5f) * 0.015625f;
                const float spp = __fadd_rn(__fmul_rn(cx, cx), __fmul_rn(cy, cy));
                const float dt  = __fmaf_rn(py, cy, __fmul_rn(px, cx));
                const float d2  = __fsub_rn(__fadd_rn(spt, spp), __fmul_rn(2.0f, dt));
                const int   p   = r * DD + c;
                // strict < keeps earlier (smaller p) on ties == top_k tie-break
                if (d2 < bd2) {
                    if (d2 < bd1) {
                        if (d2 < bd0) { bd2 = bd1; bp2 = bp1; bd1 = bd0; bp1 = bp0; bd0 = d2; bp0 = p; }
                        else          { bd2 = bd1; bp2 = bp1; bd1 = d2;  bp1 = p; }
                    } else            { bd2 = d2;  bp2 = p; }
                }
            }
        }

        const float w0 = 1.0f / fmaxf(bd0, 1e-16f);
        const float w1 = 1.0f / fmaxf(bd1, 1e-16f);
        const float w2 = 1.0f / fmaxf(bd2, 1e-16f);
        const float inv = 1.0f / (w0 + w1 + w2);

        const float* g0p = pix + ((size_t)(b * PP + bp0)) * CCH + q * 16;
        const float* g1p = pix + ((size_t)(b * PP + bp1)) * CCH + q * 16;
        const float* g2p = pix + ((size_t)(b * PP + bp2)) * CCH + q * 16;
#pragma unroll
        for (int m = 0; m < 4; ++m) {
            const float4 g0 = ((const float4*)g0p)[m];
            const float4 g1 = ((const float4*)g1p)[m];
            const float4 g2 = ((const float4*)g2p)[m];
            float s[4];
            s[0] = (w0 * g0.x + w1 * g1.x + w2 * g2.x) * inv;
            s[1] = (w0 * g0.y + w1 * g1.y + w2 * g2.y) * inv;
            s[2] = (w0 * g0.z + w1 * g1.z + w2 * g2.z) * inv;
            s[3] = (w0 * g0.w + w1 * g1.w + w2 * g2.w) * inv;
            ushort4 vh, vl;
            split_bf16(s[0], vh.x, vl.x);
            split_bf16(s[1], vh.y, vl.y);
            split_bf16(s[2], vh.z, vl.z);
            split_bf16(s[3], vh.w, vl.w);
            *(ushort4*)&h_hi[lp][q * 16 + m * 4] = vh;
            *(ushort4*)&h_lo[lp][q * 16 + m * 4] = vl;
        }
        // x part: 8 floats per thread -> channels 64 + q*8 .. +8
        const float4 xa = ((const float4*)(x + (size_t)gpt * FXF + q * 8))[0];
        const float4 xb = ((const float4*)(x + (size_t)gpt * FXF + q * 8))[1];
        ushort4 vh, vl;
        split_bf16(xa.x, vh.x, vl.x);
        split_bf16(xa.y, vh.y, vl.y);
        split_bf16(xa.z, vh.z, vl.z);
        split_bf16(xa.w, vh.w, vl.w);
        *(ushort4*)&h_hi[lp][CCH + q * 8]     = vh;
        *(ushort4*)&h_lo[lp][CCH + q * 8]     = vl;
        split_bf16(xb.x, vh.x, vl.x);
        split_bf16(xb.y, vh.y, vl.y);
        split_bf16(xb.z, vh.z, vl.z);
        split_bf16(xb.w, vh.w, vl.w);
        *(ushort4*)&h_hi[lp][CCH + q * 8 + 4] = vh;
        *(ushort4*)&h_lo[lp][CCH + q * 8 + 4] = vl;
    }
    __syncthreads();

    // ---------------- Phase B: MFMA GEMM [64 x 96] @ [96 x 256] ------------
    f32x4 acc[4][4];
#pragma unroll
    for (int m = 0; m < 4; ++m)
#pragma unroll
        for (int n = 0; n < 4; ++n)
            acc[m][n] = (f32x4)(0.0f);

    const int arow = lane & 15;          // A row within 16
    const int aoct = (lane >> 4) * 8;    // K octet base

    const unsigned short* wbase = wfrag + (size_t)wv * 3 * 2 * 4 * 512;

#pragma unroll
    for (int ks = 0; ks < KSTEPS; ++ks) {
        const unsigned short* kb = wbase + ks * 2 * 4 * 512;
        short8 Wh[4], Wl[4];
#pragma unroll
        for (int nr = 0; nr < 4; ++nr) {
            Wh[nr] = *(const short8*)(kb + (0 * 4 + nr) * 512 + lane * 8);
            Wl[nr] = *(const short8*)(kb + (1 * 4 + nr) * 512 + lane * 8);
        }
#pragma unroll
        for (int m = 0; m < 4; ++m) {
            const short8 Ah = *(const short8*)&h_hi[m * 16 + arow][ks * 32 + aoct];
            const short8 Al = *(const short8*)&h_lo[m * 16 + arow][ks * 32 + aoct];
#pragma unroll
            for (int nr = 0; nr < 4; ++nr) {
                acc[m][nr] = __builtin_amdgcn_mfma_f32_16x16x32_bf16(Ah, Wh[nr], acc[m][nr], 0, 0, 0);
                acc[m][nr] = __builtin_amdgcn_mfma_f32_16x16x32_bf16(Al, Wh[nr], acc[m][nr], 0, 0, 0);
                acc[m][nr] = __builtin_amdgcn_mfma_f32_16x16x32_bf16(Ah, Wl[nr], acc[m][nr], 0, 0, 0);
            }
        }
    }

    // ---------------- Epilogue: bias + store -------------------------------
    float bv[4];
#pragma unroll
    for (int nr = 0; nr < 4; ++nr)
        bv[nr] = bn[wv * 64 + nr * 16 + (lane & 15)];

    const int prow = (lane >> 4) * 4;    // D row group
    const int dcol = lane & 15;
#pragma unroll
    for (int m = 0; m < 4; ++m) {
#pragma unroll
        for (int nr = 0; nr < 4; ++nr) {
#pragma unroll
            for (int r = 0; r < 4; ++r) {
                const int point = pt0 + m * 16 + prow + r;
                const int dout  = wv * 64 + nr * 16 + dcol;
                out[(size_t)point * DOUT + dout] = acc[m][nr][r] + bv[nr];
            }
        }
    }
}

// ---------------------------------------------------------------------------
extern "C" void kernel_launch(void* const* d_in, const int* in_sizes, int n_in,
                              void* d_out, int out_size, void* d_ws, size_t ws_size,
                              hipStream_t stream)
{
    const float* images = (const float*)d_in[0];  // [8,64,64,64]
    const float* x      = (const float*)d_in[1];  // [32768,32]
    const float* pos    = (const float*)d_in[2];  // [32768,2]
    // d_in[3] = batch (int64)  -- recomputed as gpt>>12
    const float* W_nn   = (const float*)d_in[4];  // [96,256]
    const float* b_nn   = (const float*)d_in[5];  // [256]
    // d_in[6] = k (==3)        -- hardcoded
    float* out = (float*)d_out;

    float*          pix   = (float*)d_ws;                          // 8 MB
    unsigned short* wfrag = (unsigned short*)((char*)d_ws + 8388608); // 96 KB

    k_wsplit  <<<96, 256, 0, stream>>>(W_nn, wfrag);
    k_transpose<<<dim3(PP / 64, 1, NB), 256, 0, stream>>>(images, pix);
    k_fused   <<<NTOT / MTILE, 256, 0, stream>>>(pix, x, pos, wfrag, b_nn, out);
}

// Round 4
// 92.856 us; speedup vs baseline: 1.1768x; 1.0344x over previous
//
#include <hip/hip_runtime.h>
#include <hip/hip_bf16.h>

// Problem constants (fixed-shape problem)
#define DD    64            // H == W == 64
#define PP    4096          // pixels per image
#define NPTS  4096          // points per image
#define NB    8             // batch
#define CCH   64            // image channels
#define FXF   32            // extra features
#define KIN   96            // CCH + FXF
#define DOUT  256
#define NTOT  (NB*NPTS)     // 32768 points

#define MTILE 64            // points per block (fused kernel)
#define KSTEPS 3            // 96 / 32

typedef float  f32x4  __attribute__((ext_vector_type(4)));
typedef short  short8 __attribute__((ext_vector_type(8)));

// RNE f32 -> bf16 bits, and exact split v = hi + lo (each bf16).
__device__ __forceinline__ void split_bf16(float v, unsigned short& hi, unsigned short& lo)
{
    union { float f; unsigned u; } a;
    a.f = v;
    unsigned r = (a.u + 0x7FFFu + ((a.u >> 16) & 1u)) >> 16;   // RNE
    hi = (unsigned short)r;
    union { unsigned u; float f; } b;
    b.u = r << 16;
    float rem = v - b.f;                                        // exact (Sterbenz)
    a.f = rem;
    unsigned r2 = (a.u + 0x7FFFu + ((a.u >> 16) & 1u)) >> 16;
    lo = (unsigned short)r2;
}

// ---------------------------------------------------------------------------
// K0 (merged prep):
//   blocks [0,512):  transpose images [B][C][P] -> pix [B][P][C]
//   blocks [512,608): split W (96x256 f32) into bf16 hi/lo MFMA B-fragments
// Fragment layout: [n 4][kstep 3][pass 2][n_rep 4][lane 64][b 8] ushort;
// lane l holds W[kstep*32 + 8*(l>>4) + b][n*64 + nr*16 + (l&15)].
// ---------------------------------------------------------------------------
__global__ __launch_bounds__(256) void k_prep(const float* __restrict__ img,
                                              float* __restrict__ pix,
                                              const float* __restrict__ Wn,
                                              unsigned short* __restrict__ wfrag)
{
    __shared__ float tile[64][65];
    const int bid = blockIdx.x;

    if (bid < 512) {
        const int b  = bid >> 6;
        const int p0 = (bid & 63) * 64;
        const int t  = threadIdx.x;

        const float* src = img + (size_t)b * CCH * PP;
        float*       dst = pix + (size_t)b * PP * CCH;

        {
            const int p4 = t & 15;
            const int ch = t >> 4;
#pragma unroll
            for (int i = 0; i < 64; i += 16) {
                const float4 v = ((const float4*)(src + (size_t)(ch + i) * PP + p0))[p4];
                *(float4*)&tile[ch + i][p4 * 4] = v;
            }
        }
        __syncthreads();
        {
            const int ch = t & 63;
            const int py = t >> 6;
#pragma unroll
            for (int i = 0; i < 64; i += 4)
                dst[(size_t)(p0 + py + i) * CCH + ch] = tile[ch][py + i];
        }
    } else {
        const int t = (bid - 512) * 256 + threadIdx.x;   // 0 .. 24575
        const int b  = t & 7;
        const int l  = (t >> 3) & 63;
        const int v  = t >> 9;          // [0,48) over [n][ks][nr]
        const int nr = v & 3;
        const int w  = v >> 2;          // [0,12)
        const int ks = w % 3;
        const int n  = w / 3;

        const int k = ks * 32 + 8 * (l >> 4) + b;
        const int d = n * 64 + nr * 16 + (l & 15);
        const float val = Wn[k * DOUT + d];

        unsigned short hi, lo;
        split_bf16(val, hi, lo);
        const int base = (((n * 3 + ks) * 2 + 0) * 4 + nr) * 512 + l * 8 + b;
        const int basl = (((n * 3 + ks) * 2 + 1) * 4 + nr) * 512 + l * 8 + b;
        wfrag[base] = hi;
        wfrag[basl] = lo;
    }
}

// ---------------------------------------------------------------------------
// K1: fused  (3-NN interp -> split-bf16 h in LDS -> MFMA GEMM -> staged
//     coalesced store).  256 threads = 4 waves; tile 64 points x 256 douts.
//   Wave w: douts [64w, 64w+64) -> 4x4 fragments of 16x16, K=96 in 3 steps.
//   Split-bf16: acc += Ah*Wh + Al*Wh + Ah*Wl   (~2^-17 relative accuracy)
//   Epilogue: D -> LDS stage (aliased over dead h arrays) -> flat float4 out.
// ---------------------------------------------------------------------------
__global__ __launch_bounds__(256, 4) void k_fused(const float* __restrict__ pix,
                                                  const float* __restrict__ x,
                                                  const float* __restrict__ pos,
                                                  const unsigned short* __restrict__ wfrag,
                                                  const float* __restrict__ bn,
                                                  float* __restrict__ out)
{
    // 64 KB raw LDS: [0,12K) h_hi, [12K,24K) h_lo during GEMM;
    // whole 64 KB reused as f32 stage[64][256] for the epilogue.
    __shared__ __align__(16) char smem[65536];
    unsigned short (*h_hi)[KIN] = (unsigned short (*)[KIN])(smem);
    unsigned short (*h_lo)[KIN] = (unsigned short (*)[KIN])(smem + 12288);
    float* stage = (float*)smem;

    const int t    = threadIdx.x;
    const int lane = t & 63;
    const int wv   = t >> 6;
    const int pt0  = blockIdx.x * MTILE;

    // ---------------- Phase A: interpolation + concat (split-bf16) ---------
    {
        const int lp  = t >> 2;                   // local point 0..63
        const int q   = t & 3;                    // 16-channel slice
        const int gpt = pt0 + lp;
        const float2 pp = ((const float2*)pos)[gpt];
        const float px = pp.x;
        const float py = pp.y;
        const int   b  = gpt >> 12;               // NPTS = 4096 points/image

        // Replicate reference d2 rounding:  (|p|^2 + |c|^2) - 2*(p.c)
        const float spt = __fadd_rn(__fmul_rn(px, px), __fmul_rn(py, py));

        int cc = (int)floorf(px * 64.0f); cc = min(max(cc, 0), DD - 1);
        int rr = (int)floorf(py * 64.0f); rr = min(max(rr, 0), DD - 1);
        const int c0 = min(max(cc - 1, 0), DD - 3);
        const int r0 = min(max(rr - 1, 0), DD - 3);

        float bd0 = 1e30f, bd1 = 1e30f, bd2 = 1e30f;
        int   bp0 = 0,     bp1 = 0,     bp2 = 0;
#pragma unroll
        for (int dr = 0; dr < 3; ++dr) {
            const int   r  = r0 + dr;
            const float cy = ((float)r + 0.5f) * 0.015625f;
#pragma unroll
            for (int dc = 0; dc < 3; ++dc) {
                const int   c  = c0 + dc;
                const float cx = ((float)c + 0.5f) * 0.015625f;
                const float spp = __fadd_rn(__fmul_rn(cx, cx), __fmul_rn(cy, cy));
                const float dt  = __fmaf_rn(py, cy, __fmul_rn(px, cx));
                const float d2  = __fsub_rn(__fadd_rn(spt, spp), __fmul_rn(2.0f, dt));
                const int   p   = r * DD + c;
                // strict < keeps earlier (smaller p) on ties == top_k tie-break
                if (d2 < bd2) {
                    if (d2 < bd1) {
                        if (d2 < bd0) { bd2 = bd1; bp2 = bp1; bd1 = bd0; bp1 = bp0; bd0 = d2; bp0 = p; }
                        else          { bd2 = bd1; bp2 = bp1; bd1 = d2;  bp1 = p; }
                    } else            { bd2 = d2;  bp2 = p; }
                }
            }
        }

        const float w0 = 1.0f / fmaxf(bd0, 1e-16f);
        const float w1 = 1.0f / fmaxf(bd1, 1e-16f);
        const float w2 = 1.0f / fmaxf(bd2, 1e-16f);
        const float inv = 1.0f / (w0 + w1 + w2);

        const float* g0p = pix + ((size_t)(b * PP + bp0)) * CCH + q * 16;
        const float* g1p = pix + ((size_t)(b * PP + bp1)) * CCH + q * 16;
        const float* g2p = pix + ((size_t)(b * PP + bp2)) * CCH + q * 16;
#pragma unroll
        for (int m = 0; m < 4; ++m) {
            const float4 g0 = ((const float4*)g0p)[m];
            const float4 g1 = ((const float4*)g1p)[m];
            const float4 g2 = ((const float4*)g2p)[m];
            float s[4];
            s[0] = (w0 * g0.x + w1 * g1.x + w2 * g2.x) * inv;
            s[1] = (w0 * g0.y + w1 * g1.y + w2 * g2.y) * inv;
            s[2] = (w0 * g0.z + w1 * g1.z + w2 * g2.z) * inv;
            s[3] = (w0 * g0.w + w1 * g1.w + w2 * g2.w) * inv;
            ushort4 vh, vl;
            split_bf16(s[0], vh.x, vl.x);
            split_bf16(s[1], vh.y, vl.y);
            split_bf16(s[2], vh.z, vl.z);
            split_bf16(s[3], vh.w, vl.w);
            *(ushort4*)&h_hi[lp][q * 16 + m * 4] = vh;
            *(ushort4*)&h_lo[lp][q * 16 + m * 4] = vl;
        }
        // x part: 8 floats per thread -> channels 64 + q*8 .. +8
        const float4 xa = ((const float4*)(x + (size_t)gpt * FXF + q * 8))[0];
        const float4 xb = ((const float4*)(x + (size_t)gpt * FXF + q * 8))[1];
        ushort4 vh, vl;
        split_bf16(xa.x, vh.x, vl.x);
        split_bf16(xa.y, vh.y, vl.y);
        split_bf16(xa.z, vh.z, vl.z);
        split_bf16(xa.w, vh.w, vl.w);
        *(ushort4*)&h_hi[lp][CCH + q * 8]     = vh;
        *(ushort4*)&h_lo[lp][CCH + q * 8]     = vl;
        split_bf16(xb.x, vh.x, vl.x);
        split_bf16(xb.y, vh.y, vl.y);
        split_bf16(xb.z, vh.z, vl.z);
        split_bf16(xb.w, vh.w, vl.w);
        *(ushort4*)&h_hi[lp][CCH + q * 8 + 4] = vh;
        *(ushort4*)&h_lo[lp][CCH + q * 8 + 4] = vl;
    }
    __syncthreads();

    // ---------------- Phase B: MFMA GEMM [64 x 96] @ [96 x 256] ------------
    f32x4 acc[4][4];
#pragma unroll
    for (int m = 0; m < 4; ++m)
#pragma unroll
        for (int n = 0; n < 4; ++n)
            acc[m][n] = (f32x4)(0.0f);

    const int arow = lane & 15;          // A row within 16
    const int aoct = (lane >> 4) * 8;    // K octet base

    const unsigned short* wbase = wfrag + (size_t)wv * 3 * 2 * 4 * 512;

#pragma unroll
    for (int ks = 0; ks < KSTEPS; ++ks) {
        const unsigned short* kb = wbase + ks * 2 * 4 * 512;
        short8 Wh[4], Wl[4];
#pragma unroll
        for (int nr = 0; nr < 4; ++nr) {
            Wh[nr] = *(const short8*)(kb + (0 * 4 + nr) * 512 + lane * 8);
            Wl[nr] = *(const short8*)(kb + (1 * 4 + nr) * 512 + lane * 8);
        }
#pragma unroll
        for (int m = 0; m < 4; ++m) {
            const short8 Ah = *(const short8*)&h_hi[m * 16 + arow][ks * 32 + aoct];
            const short8 Al = *(const short8*)&h_lo[m * 16 + arow][ks * 32 + aoct];
#pragma unroll
            for (int nr = 0; nr < 4; ++nr) {
                acc[m][nr] = __builtin_amdgcn_mfma_f32_16x16x32_bf16(Ah, Wh[nr], acc[m][nr], 0, 0, 0);
                acc[m][nr] = __builtin_amdgcn_mfma_f32_16x16x32_bf16(Al, Wh[nr], acc[m][nr], 0, 0, 0);
                acc[m][nr] = __builtin_amdgcn_mfma_f32_16x16x32_bf16(Ah, Wl[nr], acc[m][nr], 0, 0, 0);
            }
        }
    }

    // ---------------- Epilogue: bias + LDS restage + coalesced store -------
    float bv[4];
#pragma unroll
    for (int nr = 0; nr < 4; ++nr)
        bv[nr] = bn[wv * 64 + nr * 16 + (lane & 15)];

    __syncthreads();   // all waves done reading h before stage overwrites it

    const int prow = (lane >> 4) * 4;    // D row group
    const int dcol = lane & 15;
#pragma unroll
    for (int m = 0; m < 4; ++m) {
#pragma unroll
        for (int nr = 0; nr < 4; ++nr) {
#pragma unroll
            for (int r = 0; r < 4; ++r) {
                const int row = m * 16 + prow + r;
                const int col = wv * 64 + nr * 16 + dcol;
                // bank swizzle: XOR bit4 of col with bit2 of row -> 2-way max
                const int colS = col ^ (((row >> 2) & 1) << 4);
                stage[row * DOUT + colS] = acc[m][nr][r] + bv[nr];
            }
        }
    }
    __syncthreads();

    // flat coalesced write-out: 16 x float4 per thread, 1KB per wave-instr
    float4* o4 = (float4*)(out + (size_t)pt0 * DOUT);
#pragma unroll
    for (int i = 0; i < 16; ++i) {
        const int fi  = t + 256 * i;          // float4 index in [0,4096)
        const int row = fi >> 6;              // /64 float4s per row
        const int col = (fi & 63) * 4;
        const int colS = col ^ (((row >> 2) & 1) << 4);
        o4[fi] = *(const float4*)&stage[row * DOUT + colS];
    }
}

// ---------------------------------------------------------------------------
extern "C" void kernel_launch(void* const* d_in, const int* in_sizes, int n_in,
                              void* d_out, int out_size, void* d_ws, size_t ws_size,
                              hipStream_t stream)
{
    const float* images = (const float*)d_in[0];  // [8,64,64,64]
    const float* x      = (const float*)d_in[1];  // [32768,32]
    const float* pos    = (const float*)d_in[2];  // [32768,2]
    // d_in[3] = batch (int64)  -- recomputed as gpt>>12
    const float* W_nn   = (const float*)d_in[4];  // [96,256]
    const float* b_nn   = (const float*)d_in[5];  // [256]
    // d_in[6] = k (==3)        -- hardcoded
    float* out = (float*)d_out;

    float*          pix   = (float*)d_ws;                             // 8 MB
    unsigned short* wfrag = (unsigned short*)((char*)d_ws + 8388608); // 96 KB

    k_prep <<<512 + 96, 256, 0, stream>>>(images, pix, W_nn, wfrag);
    k_fused<<<NTOT / MTILE, 256, 0, stream>>>(pix, x, pos, wfrag, b_nn, out);
}

// Round 5
// 90.151 us; speedup vs baseline: 1.2121x; 1.0300x over previous
//
#include <hip/hip_runtime.h>
#include <hip/hip_bf16.h>

// Problem constants (fixed-shape problem)
#define DD    64            // H == W == 64
#define PP    4096          // pixels per image
#define NPTS  4096          // points per image
#define NB    8             // batch
#define CCH   64            // image channels
#define FXF   32            // extra features
#define KIN   96            // CCH + FXF
#define DOUT  256
#define NTOT  (NB*NPTS)     // 32768 points

#define MTILE 64            // points per block (fused kernel)
#define KSTEPS 3            // 96 / 32

typedef float  f32x4  __attribute__((ext_vector_type(4)));
typedef short  short8 __attribute__((ext_vector_type(8)));

// RNE f32 -> bf16 bits, and exact split v = hi + lo (each bf16).
__device__ __forceinline__ void split_bf16(float v, unsigned short& hi, unsigned short& lo)
{
    union { float f; unsigned u; } a;
    a.f = v;
    unsigned r = (a.u + 0x7FFFu + ((a.u >> 16) & 1u)) >> 16;   // RNE
    hi = (unsigned short)r;
    union { unsigned u; float f; } b;
    b.u = r << 16;
    float rem = v - b.f;                                        // exact (Sterbenz)
    a.f = rem;
    unsigned r2 = (a.u + 0x7FFFu + ((a.u >> 16) & 1u)) >> 16;
    lo = (unsigned short)r2;
}

// ---------------------------------------------------------------------------
// K0 (merged prep):
//   blocks [0,512):  transpose images [B][C][P] -> pix [B][P][C]
//                    XCD-affine: image b handled by blocks with bid&7 == b,
//                    so image b's pix slab lands dirty in XCD b's L2.
//   blocks [512,608): split W (96x256 f32) into bf16 hi/lo MFMA B-fragments
// Fragment layout: [n 4][kstep 3][pass 2][n_rep 4][lane 64][b 8] ushort;
// lane l holds W[kstep*32 + 8*(l>>4) + b][n*64 + nr*16 + (l&15)].
// ---------------------------------------------------------------------------
__global__ __launch_bounds__(256) void k_prep(const float* __restrict__ img,
                                              float* __restrict__ pix,
                                              const float* __restrict__ Wn,
                                              unsigned short* __restrict__ wfrag)
{
    __shared__ float tile[64][65];
    const int bid = blockIdx.x;

    if (bid < 512) {
        const int b  = bid & 7;           // XCD-affine image assignment
        const int p0 = (bid >> 3) * 64;
        const int t  = threadIdx.x;

        const float* src = img + (size_t)b * CCH * PP;
        float*       dst = pix + (size_t)b * PP * CCH;

        {
            const int p4 = t & 15;
            const int ch = t >> 4;
#pragma unroll
            for (int i = 0; i < 64; i += 16) {
                const float4 v = ((const float4*)(src + (size_t)(ch + i) * PP + p0))[p4];
                *(float4*)&tile[ch + i][p4 * 4] = v;
            }
        }
        __syncthreads();
        {
            const int ch = t & 63;
            const int py = t >> 6;
#pragma unroll
            for (int i = 0; i < 64; i += 4)
                dst[(size_t)(p0 + py + i) * CCH + ch] = tile[ch][py + i];
        }
    } else {
        const int t = (bid - 512) * 256 + threadIdx.x;   // 0 .. 24575
        const int b  = t & 7;
        const int l  = (t >> 3) & 63;
        const int v  = t >> 9;          // [0,48) over [n][ks][nr]
        const int nr = v & 3;
        const int w  = v >> 2;          // [0,12)
        const int ks = w % 3;
        const int n  = w / 3;

        const int k = ks * 32 + 8 * (l >> 4) + b;
        const int d = n * 64 + nr * 16 + (l & 15);
        const float val = Wn[k * DOUT + d];

        unsigned short hi, lo;
        split_bf16(val, hi, lo);
        const int base = (((n * 3 + ks) * 2 + 0) * 4 + nr) * 512 + l * 8 + b;
        const int basl = (((n * 3 + ks) * 2 + 1) * 4 + nr) * 512 + l * 8 + b;
        wfrag[base] = hi;
        wfrag[basl] = lo;
    }
}

// ---------------------------------------------------------------------------
// K1: fused  (3-NN interp -> split-bf16 h in LDS -> MFMA GEMM -> staged
//     coalesced store).  256 threads = 4 waves; tile 64 points x 256 douts.
//   XCD-affine: bid&7 selects the image -> same XCD as k_prep's writer, so
//   pix gathers hit dirty L2 lines (no HBM round-trip for pix).
//   Wave w: douts [64w, 64w+64) -> 4x4 fragments of 16x16, K=96 in 3 steps.
//   Split-bf16: acc += Ah*Wh + Al*Wh + Ah*Wl   (~2^-17 relative accuracy)
//   ks=0 W fragments pre-issued before Phase A (latency hides under interp).
// ---------------------------------------------------------------------------
__global__ __launch_bounds__(256, 4) void k_fused(const float* __restrict__ pix,
                                                  const float* __restrict__ x,
                                                  const float* __restrict__ pos,
                                                  const unsigned short* __restrict__ wfrag,
                                                  const float* __restrict__ bn,
                                                  float* __restrict__ out)
{
    // 64 KB raw LDS: [0,12K) h_hi, [12K,24K) h_lo during GEMM;
    // whole 64 KB reused as f32 stage[64][256] for the epilogue.
    __shared__ __align__(16) char smem[65536];
    unsigned short (*h_hi)[KIN] = (unsigned short (*)[KIN])(smem);
    unsigned short (*h_lo)[KIN] = (unsigned short (*)[KIN])(smem + 12288);
    float* stage = (float*)smem;

    const int t    = threadIdx.x;
    const int lane = t & 63;
    const int wv   = t >> 6;
    const int bid  = blockIdx.x;
    const int pt0  = (bid & 7) * NPTS + (bid >> 3) * MTILE;   // XCD-affine

    // -------- early-issue: ks=0 W fragments + bias (hide under Phase A) ----
    const unsigned short* wbase = wfrag + (size_t)wv * 3 * 2 * 4 * 512;
    short8 Wh0[4], Wl0[4];
#pragma unroll
    for (int nr = 0; nr < 4; ++nr) {
        Wh0[nr] = *(const short8*)(wbase + (0 * 4 + nr) * 512 + lane * 8);
        Wl0[nr] = *(const short8*)(wbase + (1 * 4 + nr) * 512 + lane * 8);
    }
    float bv[4];
#pragma unroll
    for (int nr = 0; nr < 4; ++nr)
        bv[nr] = bn[wv * 64 + nr * 16 + (lane & 15)];

    // ---------------- Phase A: interpolation + concat (split-bf16) ---------
    {
        const int lp  = t >> 2;                   // local point 0..63
        const int q   = t & 3;                    // 16-channel slice
        const int gpt = pt0 + lp;
        const float2 pp = ((const float2*)pos)[gpt];
        const float px = pp.x;
        const float py = pp.y;
        const int   b  = gpt >> 12;               // NPTS = 4096 points/image

        // Replicate reference d2 rounding:  (|p|^2 + |c|^2) - 2*(p.c)
        const float spt = __fadd_rn(__fmul_rn(px, px), __fmul_rn(py, py));

        int cc = (int)floorf(px * 64.0f); cc = min(max(cc, 0), DD - 1);
        int rr = (int)floorf(py * 64.0f); rr = min(max(rr, 0), DD - 1);
        const int c0 = min(max(cc - 1, 0), DD - 3);
        const int r0 = min(max(rr - 1, 0), DD - 3);

        float bd0 = 1e30f, bd1 = 1e30f, bd2 = 1e30f;
        int   bp0 = 0,     bp1 = 0,     bp2 = 0;
#pragma unroll
        for (int dr = 0; dr < 3; ++dr) {
            const int   r  = r0 + dr;
            const float cy = ((float)r + 0.5f) * 0.015625f;
#pragma unroll
            for (int dc = 0; dc < 3; ++dc) {
                const int   c  = c0 + dc;
                const float cx = ((float)c + 0.5f) * 0.015625f;
                const float spp = __fadd_rn(__fmul_rn(cx, cx), __fmul_rn(cy, cy));
                const float dt  = __fmaf_rn(py, cy, __fmul_rn(px, cx));
                const float d2  = __fsub_rn(__fadd_rn(spt, spp), __fmul_rn(2.0f, dt));
                const int   p   = r * DD + c;
                // strict < keeps earlier (smaller p) on ties == top_k tie-break
                if (d2 < bd2) {
                    if (d2 < bd1) {
                        if (d2 < bd0) { bd2 = bd1; bp2 = bp1; bd1 = bd0; bp1 = bp0; bd0 = d2; bp0 = p; }
                        else          { bd2 = bd1; bp2 = bp1; bd1 = d2;  bp1 = p; }
                    } else            { bd2 = d2;  bp2 = p; }
                }
            }
        }

        const float w0 = 1.0f / fmaxf(bd0, 1e-16f);
        const float w1 = 1.0f / fmaxf(bd1, 1e-16f);
        const float w2 = 1.0f / fmaxf(bd2, 1e-16f);
        const float inv = 1.0f / (w0 + w1 + w2);

        const float* g0p = pix + ((size_t)(b * PP + bp0)) * CCH + q * 16;
        const float* g1p = pix + ((size_t)(b * PP + bp1)) * CCH + q * 16;
        const float* g2p = pix + ((size_t)(b * PP + bp2)) * CCH + q * 16;
#pragma unroll
        for (int m = 0; m < 4; ++m) {
            const float4 g0 = ((const float4*)g0p)[m];
            const float4 g1 = ((const float4*)g1p)[m];
            const float4 g2 = ((const float4*)g2p)[m];
            float s[4];
            s[0] = (w0 * g0.x + w1 * g1.x + w2 * g2.x) * inv;
            s[1] = (w0 * g0.y + w1 * g1.y + w2 * g2.y) * inv;
            s[2] = (w0 * g0.z + w1 * g1.z + w2 * g2.z) * inv;
            s[3] = (w0 * g0.w + w1 * g1.w + w2 * g2.w) * inv;
            ushort4 vh, vl;
            split_bf16(s[0], vh.x, vl.x);
            split_bf16(s[1], vh.y, vl.y);
            split_bf16(s[2], vh.z, vl.z);
            split_bf16(s[3], vh.w, vl.w);
            *(ushort4*)&h_hi[lp][q * 16 + m * 4] = vh;
            *(ushort4*)&h_lo[lp][q * 16 + m * 4] = vl;
        }
        // x part: 8 floats per thread -> channels 64 + q*8 .. +8
        const float4 xa = ((const float4*)(x + (size_t)gpt * FXF + q * 8))[0];
        const float4 xb = ((const float4*)(x + (size_t)gpt * FXF + q * 8))[1];
        ushort4 vh, vl;
        split_bf16(xa.x, vh.x, vl.x);
        split_bf16(xa.y, vh.y, vl.y);
        split_bf16(xa.z, vh.z, vl.z);
        split_bf16(xa.w, vh.w, vl.w);
        *(ushort4*)&h_hi[lp][CCH + q * 8]     = vh;
        *(ushort4*)&h_lo[lp][CCH + q * 8]     = vl;
        split_bf16(xb.x, vh.x, vl.x);
        split_bf16(xb.y, vh.y, vl.y);
        split_bf16(xb.z, vh.z, vl.z);
        split_bf16(xb.w, vh.w, vl.w);
        *(ushort4*)&h_hi[lp][CCH + q * 8 + 4] = vh;
        *(ushort4*)&h_lo[lp][CCH + q * 8 + 4] = vl;
    }
    __syncthreads();

    // ---------------- Phase B: MFMA GEMM [64 x 96] @ [96 x 256] ------------
    f32x4 acc[4][4];
#pragma unroll
    for (int m = 0; m < 4; ++m)
#pragma unroll
        for (int n = 0; n < 4; ++n)
            acc[m][n] = (f32x4)(0.0f);

    const int arow = lane & 15;          // A row within 16
    const int aoct = (lane >> 4) * 8;    // K octet base

#pragma unroll
    for (int ks = 0; ks < KSTEPS; ++ks) {
        const unsigned short* kb = wbase + ks * 2 * 4 * 512;
        short8 Wh[4], Wl[4];
#pragma unroll
        for (int nr = 0; nr < 4; ++nr) {
            if (ks == 0) { Wh[nr] = Wh0[nr]; Wl[nr] = Wl0[nr]; }
            else {
                Wh[nr] = *(const short8*)(kb + (0 * 4 + nr) * 512 + lane * 8);
                Wl[nr] = *(const short8*)(kb + (1 * 4 + nr) * 512 + lane * 8);
            }
        }
#pragma unroll
        for (int m = 0; m < 4; ++m) {
            const short8 Ah = *(const short8*)&h_hi[m * 16 + arow][ks * 32 + aoct];
            const short8 Al = *(const short8*)&h_lo[m * 16 + arow][ks * 32 + aoct];
#pragma unroll
            for (int nr = 0; nr < 4; ++nr) {
                acc[m][nr] = __builtin_amdgcn_mfma_f32_16x16x32_bf16(Ah, Wh[nr], acc[m][nr], 0, 0, 0);
                acc[m][nr] = __builtin_amdgcn_mfma_f32_16x16x32_bf16(Al, Wh[nr], acc[m][nr], 0, 0, 0);
                acc[m][nr] = __builtin_amdgcn_mfma_f32_16x16x32_bf16(Ah, Wl[nr], acc[m][nr], 0, 0, 0);
            }
        }
    }

    // ---------------- Epilogue: bias + LDS restage + coalesced store -------
    __syncthreads();   // all waves done reading h before stage overwrites it

    const int prow = (lane >> 4) * 4;    // D row group
    const int dcol = lane & 15;
#pragma unroll
    for (int m = 0; m < 4; ++m) {
#pragma unroll
        for (int nr = 0; nr < 4; ++nr) {
#pragma unroll
            for (int r = 0; r < 4; ++r) {
                const int row = m * 16 + prow + r;
                const int col = wv * 64 + nr * 16 + dcol;
                // bank swizzle: XOR bit4 of col with bit2 of row -> 2-way max
                const int colS = col ^ (((row >> 2) & 1) << 4);
                stage[row * DOUT + colS] = acc[m][nr][r] + bv[nr];
            }
        }
    }
    __syncthreads();

    // flat coalesced write-out: 16 x float4 per thread, 1KB per wave-instr
    float4* o4 = (float4*)(out + (size_t)pt0 * DOUT);
#pragma unroll
    for (int i = 0; i < 16; ++i) {
        const int fi  = t + 256 * i;          // float4 index in [0,4096)
        const int row = fi >> 6;              // /64 float4s per row
        const int col = (fi & 63) * 4;
        const int colS = col ^ (((row >> 2) & 1) << 4);
        o4[fi] = *(const float4*)&stage[row * DOUT + colS];
    }
}

// ---------------------------------------------------------------------------
extern "C" void kernel_launch(void* const* d_in, const int* in_sizes, int n_in,
                              void* d_out, int out_size, void* d_ws, size_t ws_size,
                              hipStream_t stream)
{
    const float* images = (const float*)d_in[0];  // [8,64,64,64]
    const float* x      = (const float*)d_in[1];  // [32768,32]
    const float* pos    = (const float*)d_in[2];  // [32768,2]
    // d_in[3] = batch (int64)  -- recomputed as gpt>>12
    const float* W_nn   = (const float*)d_in[4];  // [96,256]
    const float* b_nn   = (const float*)d_in[5];  // [256]
    // d_in[6] = k (==3)        -- hardcoded
    float* out = (float*)d_out;

    float*          pix   = (float*)d_ws;                             // 8 MB
    unsigned short* wfrag = (unsigned short*)((char*)d_ws + 8388608); // 96 KB

    k_prep <<<512 + 96, 256, 0, stream>>>(images, pix, W_nn, wfrag);
    k_fused<<<NTOT / MTILE, 256, 0, stream>>>(pix, x, pos, wfrag, b_nn, out);
}